// Round 20
// baseline (15686.073 us; speedup 1.0000x reference)
//
#include <hip/hip_runtime.h>

typedef __attribute__((ext_vector_type(8))) short short8;
typedef __attribute__((ext_vector_type(8))) _Float16 f16x8;
typedef __attribute__((ext_vector_type(4))) float f32x4;

#define GENF 100
#define TCOND 50
#define BATCH 128
#define HID 1024
#define INP 171
#define INPAD 192
#define OUTN 171
#define OUTPAD 176
#define SPLITS 8
#define TILES 32
#define PSTR ((size_t)BATCH * 4096)

static __device__ __forceinline__ unsigned short f2h(float f) {
  _Float16 h = (_Float16)f;
  return __builtin_bit_cast(unsigned short, h);
}
static __device__ __forceinline__ float h2f(unsigned short s) {
  return (float)__builtin_bit_cast(_Float16, s);
}
static __device__ __forceinline__ f16x8 ld8(const unsigned short* p) {
  short8 v = *reinterpret_cast<const short8*>(p);
  return __builtin_bit_cast(f16x8, v);
}
static __device__ __forceinline__ float sigm(float x) { return 1.f / (1.f + __expf(-x)); }

// Fused LSTM layer: fp16x2 split-K GEMM + parallel finisher (R19), with
// 128-col tiles (R20): TILES=32 -> A staged 32x instead of 64x per phase
// (A-from-L3 traffic halves: 64MB -> 32MB). Wave owns 32 cols (2 B-frags).
// W packed per (tile, chunk): Wp[nt][ck][128 cols][32 k] fp16.
// K-loop: 3 rotating LDS bufs, depth-2 prefetch, counted vmcnt(24)
// (12 VMEM ops/wave per super: 8 staging DMA + 4 B loads).
__global__ __launch_bounds__(256) void lstm_gemm_k(
    const unsigned short* __restrict__ xh_, const unsigned short* __restrict__ xl_,
    int ldx, int xc,
    const unsigned short* __restrict__ hh_, const unsigned short* __restrict__ hl_,
    const unsigned short* __restrict__ wP, int NKW, int nkr,
    const float* __restrict__ bias,
    float* __restrict__ c,
    unsigned short* __restrict__ ohh, unsigned short* __restrict__ ohl,
    unsigned short* __restrict__ histh, unsigned short* __restrict__ histl,
    float* __restrict__ partials, unsigned* __restrict__ counters, unsigned tgt)
{
  __shared__ __align__(16) char smem[98304];  // 3 bufs x 2 chunks x (hi 8K + lo 8K)
  const int t = threadIdx.x;
  const int lane = t & 63, wv = t >> 6;
  const int nt = blockIdx.x & (TILES - 1), sp = blockIdx.x >> 5;
  const int nit = NKW / SPLITS;  // even
  const int beg = sp * nit;
  const int ns = nit >> 1;

  const int r_row = lane & 15, kg = lane >> 4;
  const int rslot = kg ^ (r_row & 3);
  const int srow = t >> 2;
  // packed W: chunk stride = 128*32 = 4096 elems (8KB); wave's 2 col-frags
  const unsigned short* wlane = wP + ((size_t)nt * NKW) * 4096
                                + (wv * 32 + r_row) * 32 + kg * 8;
  // frag1 at +16 cols = +512 elems

  auto stage1 = [&](char* dst, int ck) {
    if (ck >= nkr) ck = 0;  // A staging clamp only (W pad chunks are zeroed)
    const unsigned short *sh, *sl;
    int ld, k0;
    if (ck < xc) { sh = xh_; sl = xl_; ld = ldx; k0 = ck * 32; }
    else { sh = hh_; sl = hl_; ld = HID; k0 = (ck - xc) * 32; }
#pragma unroll
    for (int j = 0; j < 2; ++j) {
      int rowp = j * 64 + srow;
      int slot = (t & 3) ^ (rowp & 3);
      const unsigned short* gh = sh + (size_t)rowp * ld + k0 + slot * 8;
      const unsigned short* gl = sl + (size_t)rowp * ld + k0 + slot * 8;
      char* dh = dst + j * 4096 + wv * 1024;
      char* dl = dst + 8192 + j * 4096 + wv * 1024;
      __builtin_amdgcn_global_load_lds((const __attribute__((address_space(1))) void*)gh,
                                       (__attribute__((address_space(3))) void*)dh, 16, 0, 0);
      __builtin_amdgcn_global_load_lds((const __attribute__((address_space(1))) void*)gl,
                                       (__attribute__((address_space(3))) void*)dl, 16, 0, 0);
    }
  };

  f32x4 zz = {0.f, 0.f, 0.f, 0.f};
  f32x4 acc0[8] = {zz, zz, zz, zz, zz, zz, zz, zz};
  f32x4 acc1[8] = {zz, zz, zz, zz, zz, zz, zz, zz};

  char* bA = smem;
  char* bB = smem + 32768;
  char* bC = smem + 65536;

  stage1(bA, beg);
  stage1(bA + 16384, beg + 1);
  f16x8 b0h0 = ld8(wlane + (size_t)(beg + 0) * 4096);
  f16x8 b0g0 = ld8(wlane + (size_t)(beg + 0) * 4096 + 512);
  f16x8 b0h1 = ld8(wlane + (size_t)(beg + 1) * 4096);
  f16x8 b0g1 = ld8(wlane + (size_t)(beg + 1) * 4096 + 512);
  __builtin_amdgcn_sched_barrier(0);
  stage1(bB, beg + 2);
  stage1(bB + 16384, beg + 3);
  f16x8 b1h0 = ld8(wlane + (size_t)(beg + 2) * 4096);
  f16x8 b1g0 = ld8(wlane + (size_t)(beg + 2) * 4096 + 512);
  f16x8 b1h1 = ld8(wlane + (size_t)(beg + 3) * 4096);
  f16x8 b1g1 = ld8(wlane + (size_t)(beg + 3) * 4096 + 512);
  __builtin_amdgcn_sched_barrier(0);

  for (int i = 0; i < ns; ++i) {
    int ck = beg + 2 * i + 4;
    if (ck >= beg + nit) ck = beg;  // junk tail (uniform counts, unused)
    stage1(bC, ck);
    stage1(bC + 16384, ck + 1);
    f16x8 b2h0 = ld8(wlane + (size_t)ck * 4096);
    f16x8 b2g0 = ld8(wlane + (size_t)ck * 4096 + 512);
    f16x8 b2h1 = ld8(wlane + (size_t)(ck + 1) * 4096);
    f16x8 b2g1 = ld8(wlane + (size_t)(ck + 1) * 4096 + 512);
    __builtin_amdgcn_sched_barrier(0);

    // wait: current super retired (24 = 2 supers x 12 VMEM stay in flight)
    asm volatile("s_waitcnt vmcnt(24)" ::: "memory");
    __builtin_amdgcn_s_barrier();
    __builtin_amdgcn_sched_barrier(0);

#pragma unroll
    for (int ch = 0; ch < 2; ++ch) {
      f16x8 ah[8], al[8];
#pragma unroll
      for (int rg = 0; rg < 8; ++rg) {
        int ro = ch * 16384 + (rg * 16 + r_row) * 64 + rslot * 16;
        ah[rg] = *reinterpret_cast<const f16x8*>(bA + ro);
        al[rg] = *reinterpret_cast<const f16x8*>(bA + ro + 8192);
      }
      f16x8 BH = ch ? b0h1 : b0h0;
      f16x8 BG = ch ? b0g1 : b0g0;
#pragma unroll
      for (int rg = 0; rg < 8; ++rg)
        acc0[rg] = __builtin_amdgcn_mfma_f32_16x16x32_f16(ah[rg], BH, acc0[rg], 0, 0, 0);
#pragma unroll
      for (int rg = 0; rg < 8; ++rg)
        acc0[rg] = __builtin_amdgcn_mfma_f32_16x16x32_f16(al[rg], BH, acc0[rg], 0, 0, 0);
#pragma unroll
      for (int rg = 0; rg < 8; ++rg)
        acc1[rg] = __builtin_amdgcn_mfma_f32_16x16x32_f16(ah[rg], BG, acc1[rg], 0, 0, 0);
#pragma unroll
      for (int rg = 0; rg < 8; ++rg)
        acc1[rg] = __builtin_amdgcn_mfma_f32_16x16x32_f16(al[rg], BG, acc1[rg], 0, 0, 0);
    }
    __builtin_amdgcn_sched_barrier(0);
    __builtin_amdgcn_s_barrier();

    char* tmp = bA; bA = bB; bB = bC; bC = tmp;
    b0h0 = b1h0; b0g0 = b1g0; b0h1 = b1h1; b0g1 = b1g1;
    b1h0 = b2h0; b1g0 = b2g0; b1h1 = b2h1; b1g1 = b2g1;
  }

  // ---- store split partials ----
  {
    float* pb = partials + (size_t)sp * PSTR;
    const int cn0 = nt * 128 + wv * 32 + r_row;
    const int mb = kg * 4;
#pragma unroll
    for (int rg = 0; rg < 8; ++rg)
#pragma unroll
      for (int r = 0; r < 4; ++r) {
        pb[(size_t)(rg * 16 + mb + r) * 4096 + cn0] = acc0[rg][r];
        pb[(size_t)(rg * 16 + mb + r) * 4096 + cn0 + 16] = acc1[rg][r];
      }
  }

  __syncthreads();  // drain stores + junk staging
  if (t == 0) {
    __hip_atomic_fetch_add(&counters[nt], 1u, __ATOMIC_RELEASE, __HIP_MEMORY_SCOPE_AGENT);
    while (__hip_atomic_load(&counters[nt], __ATOMIC_RELAXED, __HIP_MEMORY_SCOPE_AGENT) < tgt)
      __builtin_amdgcn_s_sleep(2);
    (void)__hip_atomic_load(&counters[nt], __ATOMIC_ACQUIRE, __HIP_MEMORY_SCOPE_AGENT);
  }
  __syncthreads();

  // ---- parallel finisher: this block handles rows [sp*16, sp*16+16) ----
  const int fc = t & 31, fm = t >> 5;  // 32 nh cols x 8 rows per pass
  const int nh = nt * 32 + fc;
  const f32x4 bv = *reinterpret_cast<const f32x4*>(&bias[nh * 4]);
#pragma unroll
  for (int p = 0; p < 2; ++p) {
    int m = sp * 16 + p * 8 + fm;
    size_t gi0 = (size_t)m * 4096 + nh * 4;
    f32x4 s = *reinterpret_cast<const f32x4*>(&partials[gi0]);
#pragma unroll
    for (int q = 1; q < SPLITS; ++q)
      s += *reinterpret_cast<const f32x4*>(&partials[gi0 + (size_t)q * PSTR]);
    float gi = sigm(s[0] + bv[0]);
    float gf = sigm(s[1] + bv[1]);
    float gg = tanhf(s[2] + bv[2]);
    float go = sigm(s[3] + bv[3]);
    size_t sidx = (size_t)m * HID + nh;
    float cn2 = gf * c[sidx] + gi * gg;
    c[sidx] = cn2;
    float h = go * tanhf(cn2);
    unsigned short h16 = f2h(h);
    unsigned short l16 = f2h(h - h2f(h16));
    ohh[sidx] = h16;
    ohl[sidx] = l16;
    if (histh) { histh[sidx] = h16; histl[sidx] = l16; }
  }
}

// Batched decoder over history: out[b][t][:] = hist[t*128+b] @ wd^T + bd.
__global__ __launch_bounds__(256) void decb_k(
    const unsigned short* __restrict__ histh, const unsigned short* __restrict__ histl,
    const unsigned short* __restrict__ wdh, const float* __restrict__ bd,
    float* __restrict__ outp)
{
  const int wave = threadIdx.x >> 6, lane = threadIdx.x & 63;
  const int n0 = ((int)blockIdx.x % 11) * 16;
  const int m0 = ((int)blockIdx.x / 11) * 16;
  const int row = lane & 15, kg = lane >> 4;
  f32x4 acc = {0.f, 0.f, 0.f, 0.f};
  const unsigned short* pah = histh + (size_t)(m0 + row) * HID + kg * 8 + wave * 256;
  const unsigned short* pal = histl + (size_t)(m0 + row) * HID + kg * 8 + wave * 256;
  const unsigned short* pbh = wdh + (size_t)(n0 + row) * HID + kg * 8 + wave * 256;
#pragma unroll
  for (int kk = 0; kk < 8; ++kk) {
    int off = kk * 32;
    f16x8 a1 = ld8(pah + off), a2 = ld8(pal + off);
    f16x8 b1 = ld8(pbh + off);
    acc = __builtin_amdgcn_mfma_f32_16x16x32_f16(a1, b1, acc, 0, 0, 0);
    acc = __builtin_amdgcn_mfma_f32_16x16x32_f16(a2, b1, acc, 0, 0, 0);
  }
  __shared__ f32x4 red[4][64];
  if (wave) red[wave][lane] = acc;
  __syncthreads();
  if (wave == 0) {
    acc += red[1][lane];
    acc += red[2][lane];
    acc += red[3][lane];
    const int col = lane & 15, rg = lane >> 4;
#pragma unroll
    for (int r = 0; r < 4; ++r) {
      int m = m0 + rg * 4 + r;
      int n = n0 + col;
      if (n < OUTN) {
        int tt = m >> 7, b = m & 127;
        outp[(size_t)b * (GENF * OUTN) + (size_t)tt * OUTN + n] = acc[r] + bd[n];
      }
    }
  }
}

// ---- prep kernels ----
// LSTM weight -> PACKED (128-col tiles): perm row rp=(r&1023)*4+(r>>10);
// dst[((nt*NKW + ck0 + cc/32)*128 + (rp&127))*32 + cc%32], nt = rp>>7.
__global__ void cvt_w_pack_k(const float* __restrict__ src, unsigned short* __restrict__ dst,
                             int C, int Cpad, int ck0, int NKW)
{
  int idx = blockIdx.x * 256 + threadIdx.x;
  if (idx >= 4096 * Cpad) return;
  int r = idx / Cpad, cc = idx - r * Cpad;
  float v = (cc < C) ? src[(size_t)r * C + cc] : 0.f;
  int rp = (r & 1023) * 4 + (r >> 10);
  int nt = rp >> 7, nc = rp & 127;
  int ck = ck0 + (cc >> 5), kk = cc & 31;
  dst[(((size_t)nt * NKW + ck) * 128 + nc) * 32 + kk] = f2h(v);
}

// plain fp16 cvt with row/col pad (no perm)
__global__ void cvt_plain_k(const float* __restrict__ src, unsigned short* __restrict__ w16,
                            int R, int C, int Rp, int Cp)
{
  int idx = blockIdx.x * 256 + threadIdx.x;
  if (idx >= Rp * Cp) return;
  int r = idx / Cp, c2 = idx - r * Cp;
  float v = (r < R && c2 < C) ? src[(size_t)r * C + c2] : 0.f;
  w16[idx] = f2h(v);
}

// transposed dec weight: wdt[k][j] = w_dec[j][k], [1024][192] fp16 (pad j>=171 -> 0)
__global__ void cvt_wdt_k(const float* __restrict__ wdec, unsigned short* __restrict__ wdt)
{
  int idx = blockIdx.x * 256 + threadIdx.x;
  if (idx >= 1024 * 192) return;
  int k = idx / 192, j = idx - k * 192;
  float v = (j < OUTN) ? wdec[(size_t)j * HID + k] : 0.f;
  wdt[idx] = f2h(v);
}

// Weff = Wih1 @ Wd : [4096 perm rows][1024], written PACKED (128-col tiles)
// into W1g chunks 0..31.
__global__ __launch_bounds__(256) void weff_k(
    const unsigned short* __restrict__ wih, const unsigned short* __restrict__ wdt,
    unsigned short* __restrict__ W1g)
{
  const int wave = threadIdx.x >> 6, lane = threadIdx.x & 63;
  const int tile = blockIdx.x * 4 + wave;
  const int m0 = (tile >> 6) * 16;   // i
  const int n0 = (tile & 63) * 16;   // k2
  const int row = lane & 15, kg = lane >> 4;
  f32x4 acc = {0.f, 0.f, 0.f, 0.f};
  const unsigned short* pa = wih + (size_t)(m0 + row) * 192 + kg * 8;
  const unsigned short* pb = wdt + (size_t)(n0 + row) * 192 + kg * 8;
#pragma unroll
  for (int kk = 0; kk < 6; ++kk) {
    int off = kk * 32;
    f16x8 a = ld8(pa + off);
    f16x8 b = ld8(pb + off);
    acc = __builtin_amdgcn_mfma_f32_16x16x32_f16(a, b, acc, 0, 0, 0);
  }
  const int col = lane & 15, rg = lane >> 4;
#pragma unroll
  for (int r = 0; r < 4; ++r) {
    int i = m0 + rg * 4 + r;
    int k2 = n0 + col;
    int rp = (i & 1023) * 4 + (i >> 10);
    int nt = rp >> 7, nc = rp & 127;
    int ck = k2 >> 5, kk2 = k2 & 31;
    W1g[(((size_t)nt * 64 + ck) * 128 + nc) * 32 + kk2] = f2h(acc[r]);
  }
}

// beff[rp(i)] = b_ih1[i] + b_hh1[i] + sum_j Wih1[i][j] * b_dec[j]  (fp32)
__global__ void beff_k(const float* __restrict__ wih1, const float* __restrict__ bih,
                       const float* __restrict__ bhh, const float* __restrict__ bdec,
                       float* __restrict__ dst)
{
  int i = blockIdx.x * 256 + threadIdx.x;
  if (i >= 4096) return;
  float a = bih[i] + bhh[i];
  for (int j = 0; j < OUTN; ++j) a += wih1[(size_t)i * OUTN + j] * bdec[j];
  dst[(i & 1023) * 4 + (i >> 10)] = a;
}

__global__ void bias_perm_k(const float* __restrict__ a, const float* __restrict__ b,
                            float* __restrict__ dst)
{
  int i = blockIdx.x * 256 + threadIdx.x;
  if (i < 4096) dst[(i & 1023) * 4 + (i >> 10)] = a[i] + b[i];
}

__global__ void biaspad_k(const float* __restrict__ a, float* __restrict__ dst, int n, int np)
{
  int i = blockIdx.x * 256 + threadIdx.x;
  if (i < np) dst[i] = (i < n) ? a[i] : 0.f;
}

// initial_seq [B][T][IN] fp32 -> xcond hi/lo [T][B][INPAD] fp16
__global__ void xcond_k(const float* __restrict__ seq, unsigned short* __restrict__ xhi,
                        unsigned short* __restrict__ xlo)
{
  int idx = blockIdx.x * 256 + threadIdx.x;
  const int total = TCOND * BATCH * INPAD;
  if (idx >= total) return;
  int t = idx / (BATCH * INPAD);
  int rem = idx - t * (BATCH * INPAD);
  int b = rem / INPAD;
  int k = rem - b * INPAD;
  float v = (k < INP) ? seq[((size_t)b * TCOND + t) * INP + k] : 0.f;
  unsigned short h = f2h(v);
  xhi[idx] = h;
  xlo[idx] = f2h(v - h2f(h));
}

extern "C" void kernel_launch(void* const* d_in, const int* in_sizes, int n_in,
                              void* d_out, int out_size, void* d_ws, size_t ws_size,
                              hipStream_t stream)
{
  (void)in_sizes; (void)n_in; (void)out_size;
  const float* seq   = (const float*)d_in[0];
  const float* w_ih1 = (const float*)d_in[2];
  const float* w_hh1 = (const float*)d_in[3];
  const float* b_ih1 = (const float*)d_in[4];
  const float* b_hh1 = (const float*)d_in[5];
  const float* w_ih2 = (const float*)d_in[6];
  const float* w_hh2 = (const float*)d_in[7];
  const float* b_ih2 = (const float*)d_in[8];
  const float* b_hh2 = (const float*)d_in[9];
  const float* w_ih3 = (const float*)d_in[10];
  const float* w_hh3 = (const float*)d_in[11];
  const float* b_ih3 = (const float*)d_in[12];
  const float* b_hh3 = (const float*)d_in[13];
  const float* w_dec = (const float*)d_in[14];
  const float* b_dec = (const float*)d_in[15];
  float* out = (float*)d_out;

  char* ws = (char*)d_ws;
  size_t off = 0;
  auto alloc = [&](size_t bytes) -> char* {
    off = (off + 255) & ~(size_t)255;
    char* p = ws + off;
    off += bytes;
    return p;
  };
  auto us = [&](size_t n) { return (unsigned short*)alloc(n * 2); };
  auto fl = [&](size_t n) { return (float*)alloc(n * 4); };

  const int NK1C = 48;  // cond L1: 6 x-chunks + 32 h-chunks = 38 real, pad to 48
  const int NK2 = 64;   // gen L1 / L2 / L3: 32 x + 32 h
  unsigned short* W1c = us((size_t)4096 * NK1C * 32);   // packed
  unsigned short* W1g = us((size_t)4096 * NK2 * 32);    // packed: ck0-31 Weff, 32-63 Whh1
  unsigned short* W2 = us((size_t)4096 * NK2 * 32);     // packed: Wih2 | Whh2
  unsigned short* W3 = us((size_t)4096 * NK2 * 32);     // packed: Wih3 | Whh3
  unsigned short* wd = us((size_t)OUTPAD * HID);
  unsigned short* wih1f = us((size_t)4096 * 192);
  unsigned short* wdt = us((size_t)1024 * 192);
  float *b1c = fl(4096), *beff = fl(4096), *b2 = fl(4096), *b3 = fl(4096), *bd = fl(OUTPAD);
  unsigned short *xch = us((size_t)TCOND * BATCH * INPAD), *xcl = us((size_t)TCOND * BATCH * INPAD);
  float* partials = fl((size_t)SPLITS * PSTR);
  unsigned short* histh = us((size_t)GENF * BATCH * HID);
  unsigned short* histl = us((size_t)GENF * BATCH * HID);

  size_t state_beg = (off + 255) & ~(size_t)255;
  float *c0 = fl((size_t)BATCH * HID), *c1 = fl((size_t)BATCH * HID), *c2 = fl((size_t)BATCH * HID);
  unsigned short* Hh[3][2];
  unsigned short* Hl[3][2];
  for (int L = 0; L < 3; ++L)
    for (int p = 0; p < 2; ++p) {
      Hh[L][p] = us((size_t)BATCH * HID);
      Hl[L][p] = us((size_t)BATCH * HID);
    }
  unsigned* counters = (unsigned*)alloc(3 * TILES * 4);  // monotonic, zeroed each call
  size_t state_end = off;

  if (off > ws_size) return;  // scratch too small; fail visibly

  hipMemsetAsync(ws + state_beg, 0, state_end - state_beg, stream);
  // zero W1c pad chunks (38..47)
  hipMemsetAsync(W1c, 0, (size_t)4096 * NK1C * 32 * 2, stream);

  // ---- weight / input prep ----
  cvt_w_pack_k<<<(4096 * INPAD + 255) / 256, 256, 0, stream>>>(w_ih1, W1c, INP, INPAD, 0, NK1C);
  cvt_w_pack_k<<<(4096 * 1024 + 255) / 256, 256, 0, stream>>>(w_hh1, W1c, HID, HID, 6, NK1C);
  cvt_w_pack_k<<<(4096 * 1024 + 255) / 256, 256, 0, stream>>>(w_hh1, W1g, HID, HID, 32, NK2);
  cvt_w_pack_k<<<(4096 * 1024 + 255) / 256, 256, 0, stream>>>(w_ih2, W2, HID, HID, 0, NK2);
  cvt_w_pack_k<<<(4096 * 1024 + 255) / 256, 256, 0, stream>>>(w_hh2, W2, HID, HID, 32, NK2);
  cvt_w_pack_k<<<(4096 * 1024 + 255) / 256, 256, 0, stream>>>(w_ih3, W3, HID, HID, 0, NK2);
  cvt_w_pack_k<<<(4096 * 1024 + 255) / 256, 256, 0, stream>>>(w_hh3, W3, HID, HID, 32, NK2);
  cvt_plain_k<<<(OUTPAD * HID + 255) / 256, 256, 0, stream>>>(w_dec, wd, OUTN, HID, OUTPAD, HID);
  cvt_plain_k<<<(4096 * 192 + 255) / 256, 256, 0, stream>>>(w_ih1, wih1f, 4096, INP, 4096, 192);
  cvt_wdt_k<<<(1024 * 192 + 255) / 256, 256, 0, stream>>>(w_dec, wdt);
  weff_k<<<4096, 256, 0, stream>>>(wih1f, wdt, W1g);
  beff_k<<<16, 256, 0, stream>>>(w_ih1, b_ih1, b_hh1, b_dec, beff);
  bias_perm_k<<<16, 256, 0, stream>>>(b_ih1, b_hh1, b1c);
  bias_perm_k<<<16, 256, 0, stream>>>(b_ih2, b_hh2, b2);
  bias_perm_k<<<16, 256, 0, stream>>>(b_ih3, b_hh3, b3);
  biaspad_k<<<1, 256, 0, stream>>>(b_dec, bd, OUTN, OUTPAD);
  xcond_k<<<(TCOND * BATCH * INPAD + 255) / 256, 256, 0, stream>>>(seq, xch, xcl);

  // ---- recurrent loop: 3 dispatches per step (decoder folded into gen-L1) ----
  for (int s = 0; s < TCOND + GENF; ++s) {
    const int pp = s & 1, np = pp ^ 1;
    const unsigned tg = (unsigned)SPLITS * (unsigned)(s + 1);
    unsigned short *hsh = (unsigned short*)0, *hsl = (unsigned short*)0;
    if (s >= TCOND) {
      hsh = histh + (size_t)(s - TCOND) * BATCH * HID;
      hsl = histl + (size_t)(s - TCOND) * BATCH * HID;
    }
    if (s < TCOND) {
      lstm_gemm_k<<<TILES * SPLITS, 256, 0, stream>>>(
          xch + (size_t)s * BATCH * INPAD, xcl + (size_t)s * BATCH * INPAD, INPAD, 6,
          Hh[0][pp], Hl[0][pp], W1c, NK1C, 38, b1c, c0,
          Hh[0][np], Hl[0][np], (unsigned short*)0, (unsigned short*)0,
          partials, counters, tg);
    } else {
      lstm_gemm_k<<<TILES * SPLITS, 256, 0, stream>>>(
          Hh[2][pp], Hl[2][pp], HID, 32,
          Hh[0][pp], Hl[0][pp], W1g, NK2, NK2, beff, c0,
          Hh[0][np], Hl[0][np], (unsigned short*)0, (unsigned short*)0,
          partials, counters, tg);
    }
    lstm_gemm_k<<<TILES * SPLITS, 256, 0, stream>>>(
        Hh[0][np], Hl[0][np], HID, 32,
        Hh[1][pp], Hl[1][pp], W2, NK2, NK2, b2, c1,
        Hh[1][np], Hl[1][np], (unsigned short*)0, (unsigned short*)0,
        partials, counters + TILES, tg);
    lstm_gemm_k<<<TILES * SPLITS, 256, 0, stream>>>(
        Hh[1][np], Hl[1][np], HID, 32,
        Hh[2][pp], Hl[2][pp], W3, NK2, NK2, b3, c2,
        Hh[2][np], Hl[2][np], hsh, hsl,
        partials, counters + 2 * TILES, tg);
  }

  // ---- batched decoder: all 100 outputs in one GEMM ----
  decb_k<<<(GENF * BATCH / 16) * 11, 256, 0, stream>>>(histh, histl, wd, bd, out);
}

// Round 21
// 11304.178 us; speedup vs baseline: 1.3876x; 1.3876x over previous
//
#include <hip/hip_runtime.h>

typedef __attribute__((ext_vector_type(8))) short short8;
typedef __attribute__((ext_vector_type(8))) _Float16 f16x8;
typedef __attribute__((ext_vector_type(4))) float f32x4;

#define GENF 100
#define TCOND 50
#define BATCH 128
#define HID 1024
#define INP 171
#define INPAD 192
#define OUTN 171
#define OUTPAD 176
#define SPLITS 4
#define TILES 64
#define PSTR ((size_t)BATCH * 4096)

static __device__ __forceinline__ unsigned short f2h(float f) {
  _Float16 h = (_Float16)f;
  return __builtin_bit_cast(unsigned short, h);
}
static __device__ __forceinline__ float h2f(unsigned short s) {
  return (float)__builtin_bit_cast(_Float16, s);
}
static __device__ __forceinline__ f16x8 ld8(const unsigned short* p) {
  short8 v = *reinterpret_cast<const short8*>(p);
  return __builtin_bit_cast(f16x8, v);
}
static __device__ __forceinline__ float sigm(float x) { return 1.f / (1.f + __expf(-x)); }

// Fused LSTM layer: fp16x2 split-K GEMM + parallel finisher (R19 structure).
// W packed per (tile, chunk): Wp[nt][ck][64 cols][32 k] fp16.
// K-loop (R21): 3 rotating LDS bufs, depth-2 prefetch with PEELED EPILOGUE —
// only real supers are staged; last two iters wait with counted vmcnt(10)/(0)
// (10 VMEM ops/super/wave: 8 staging DMA + 2 B loads). No junk-tail staging.
// Finisher: monotonic counters (target per launch; memset resets per replay);
// all 4 split-blocks arrive+poll, then each applies the cell to its 32 rows.
__global__ __launch_bounds__(256) void lstm_gemm_k(
    const unsigned short* __restrict__ xh_, const unsigned short* __restrict__ xl_,
    int ldx, int xc,
    const unsigned short* __restrict__ hh_, const unsigned short* __restrict__ hl_,
    const unsigned short* __restrict__ wP, int NKW, int nkr,
    const float* __restrict__ bias,
    float* __restrict__ c,
    unsigned short* __restrict__ ohh, unsigned short* __restrict__ ohl,
    unsigned short* __restrict__ histh, unsigned short* __restrict__ histl,
    float* __restrict__ partials, unsigned* __restrict__ counters, unsigned tgt)
{
  __shared__ __align__(16) char smem[98304];  // 3 bufs x 2 chunks x (hi 8K + lo 8K)
  const int t = threadIdx.x;
  const int lane = t & 63, wv = t >> 6;
  const int nt = blockIdx.x & (TILES - 1), sp = blockIdx.x >> 6;
  const int nit = NKW / SPLITS;  // even
  const int beg = sp * nit;
  const int ns = nit >> 1;       // super-iters (>=3)

  const int r_row = lane & 15, kg = lane >> 4;
  const int rslot = kg ^ (r_row & 3);
  const int srow = t >> 2;
  // packed W: lane's base within a chunk; chunk stride = 2048 elements (4KB)
  const unsigned short* wlane = wP + ((size_t)nt * NKW) * 2048
                                + (wv * 16 + r_row) * 32 + kg * 8;

  auto stage1 = [&](char* dst, int ck) {
    if (ck >= nkr) ck = 0;  // A staging clamp only (W pad chunks are zeroed)
    const unsigned short *sh, *sl;
    int ld, k0;
    if (ck < xc) { sh = xh_; sl = xl_; ld = ldx; k0 = ck * 32; }
    else { sh = hh_; sl = hl_; ld = HID; k0 = (ck - xc) * 32; }
#pragma unroll
    for (int j = 0; j < 2; ++j) {
      int rowp = j * 64 + srow;
      int slot = (t & 3) ^ (rowp & 3);
      const unsigned short* gh = sh + (size_t)rowp * ld + k0 + slot * 8;
      const unsigned short* gl = sl + (size_t)rowp * ld + k0 + slot * 8;
      char* dh = dst + j * 4096 + wv * 1024;
      char* dl = dst + 8192 + j * 4096 + wv * 1024;
      __builtin_amdgcn_global_load_lds((const __attribute__((address_space(1))) void*)gh,
                                       (__attribute__((address_space(3))) void*)dh, 16, 0, 0);
      __builtin_amdgcn_global_load_lds((const __attribute__((address_space(1))) void*)gl,
                                       (__attribute__((address_space(3))) void*)dl, 16, 0, 0);
    }
  };

  f32x4 zz = {0.f, 0.f, 0.f, 0.f};
  f32x4 acc[8] = {zz, zz, zz, zz, zz, zz, zz, zz};

  char* bA = smem;
  char* bB = smem + 32768;
  char* bC = smem + 65536;

  // prologue: supers 0 and 1 in flight (10 VMEM ops/wave each)
  stage1(bA, beg);
  stage1(bA + 16384, beg + 1);
  f16x8 b0h0 = ld8(wlane + (size_t)(beg + 0) * 2048);
  f16x8 b0h1 = ld8(wlane + (size_t)(beg + 1) * 2048);
  __builtin_amdgcn_sched_barrier(0);
  stage1(bB, beg + 2);
  stage1(bB + 16384, beg + 3);
  f16x8 b1h0 = ld8(wlane + (size_t)(beg + 2) * 2048);
  f16x8 b1h1 = ld8(wlane + (size_t)(beg + 3) * 2048);
  __builtin_amdgcn_sched_barrier(0);
  f16x8 b2h0 = b0h0, b2h1 = b0h1;  // dummy init; only read when staged

  for (int i = 0; i < ns; ++i) {
    if (i + 2 < ns) {
      // stage real super i+2; wait super i retired (2 supers = 20 ops in flight)
      int ck = beg + 2 * i + 4;
      stage1(bC, ck);
      stage1(bC + 16384, ck + 1);
      b2h0 = ld8(wlane + (size_t)ck * 2048);
      b2h1 = ld8(wlane + (size_t)(ck + 1) * 2048);
      __builtin_amdgcn_sched_barrier(0);
      asm volatile("s_waitcnt vmcnt(20)" ::: "memory");
    } else if (i + 2 == ns) {
      // no stage; supers i, i+1 outstanding; wait super i (leave 10 ops)
      asm volatile("s_waitcnt vmcnt(10)" ::: "memory");
    } else {
      // last iter: only super i outstanding; drain
      asm volatile("s_waitcnt vmcnt(0)" ::: "memory");
    }
    __builtin_amdgcn_s_barrier();
    __builtin_amdgcn_sched_barrier(0);

#pragma unroll
    for (int ch = 0; ch < 2; ++ch) {
      f16x8 ah[8], al[8];
#pragma unroll
      for (int rg = 0; rg < 8; ++rg) {
        int ro = ch * 16384 + (rg * 16 + r_row) * 64 + rslot * 16;
        ah[rg] = *reinterpret_cast<const f16x8*>(bA + ro);
        al[rg] = *reinterpret_cast<const f16x8*>(bA + ro + 8192);
      }
      f16x8 BH = ch ? b0h1 : b0h0;
#pragma unroll
      for (int rg = 0; rg < 8; ++rg)
        acc[rg] = __builtin_amdgcn_mfma_f32_16x16x32_f16(ah[rg], BH, acc[rg], 0, 0, 0);
#pragma unroll
      for (int rg = 0; rg < 8; ++rg)
        acc[rg] = __builtin_amdgcn_mfma_f32_16x16x32_f16(al[rg], BH, acc[rg], 0, 0, 0);
    }
    __builtin_amdgcn_sched_barrier(0);
    __builtin_amdgcn_s_barrier();  // all waves done reading bA before restage

    char* tmp = bA; bA = bB; bB = bC; bC = tmp;
    b0h0 = b1h0; b0h1 = b1h1;
    b1h0 = b2h0; b1h1 = b2h1;
  }

  // ---- store split partials ----
  {
    float* pb = partials + (size_t)sp * PSTR;
    const int cn = nt * 64 + wv * 16 + r_row;
    const int mb = kg * 4;
#pragma unroll
    for (int rg = 0; rg < 8; ++rg)
#pragma unroll
      for (int r = 0; r < 4; ++r)
        pb[(size_t)(rg * 16 + mb + r) * 4096 + cn] = acc[rg][r];
  }

  __syncthreads();  // drain stores
  if (t == 0) {
    __hip_atomic_fetch_add(&counters[nt], 1u, __ATOMIC_RELEASE, __HIP_MEMORY_SCOPE_AGENT);
    while (__hip_atomic_load(&counters[nt], __ATOMIC_RELAXED, __HIP_MEMORY_SCOPE_AGENT) < tgt)
      __builtin_amdgcn_s_sleep(2);
    (void)__hip_atomic_load(&counters[nt], __ATOMIC_ACQUIRE, __HIP_MEMORY_SCOPE_AGENT);
  }
  __syncthreads();

  // ---- parallel finisher: this block handles rows [sp*32, sp*32+32) ----
  const int fc = t & 15, fm = t >> 4;
  const int nh = nt * 16 + fc;
  const f32x4 bv = *reinterpret_cast<const f32x4*>(&bias[nh * 4]);
#pragma unroll
  for (int p = 0; p < 2; ++p) {
    int m = sp * 32 + p * 16 + fm;
    size_t gi0 = (size_t)m * 4096 + nh * 4;
    f32x4 s = *reinterpret_cast<const f32x4*>(&partials[gi0]);
#pragma unroll
    for (int q = 1; q < SPLITS; ++q)
      s += *reinterpret_cast<const f32x4*>(&partials[gi0 + (size_t)q * PSTR]);
    float gi = sigm(s[0] + bv[0]);
    float gf = sigm(s[1] + bv[1]);
    float gg = tanhf(s[2] + bv[2]);
    float go = sigm(s[3] + bv[3]);
    size_t sidx = (size_t)m * HID + nh;
    float cn2 = gf * c[sidx] + gi * gg;
    c[sidx] = cn2;
    float h = go * tanhf(cn2);
    unsigned short h16 = f2h(h);
    unsigned short l16 = f2h(h - h2f(h16));
    ohh[sidx] = h16;
    ohl[sidx] = l16;
    if (histh) { histh[sidx] = h16; histl[sidx] = l16; }
  }
}

// Batched decoder over history: out[b][t][:] = hist[t*128+b] @ wd^T + bd.
__global__ __launch_bounds__(256) void decb_k(
    const unsigned short* __restrict__ histh, const unsigned short* __restrict__ histl,
    const unsigned short* __restrict__ wdh, const float* __restrict__ bd,
    float* __restrict__ outp)
{
  const int wave = threadIdx.x >> 6, lane = threadIdx.x & 63;
  const int n0 = ((int)blockIdx.x % 11) * 16;
  const int m0 = ((int)blockIdx.x / 11) * 16;
  const int row = lane & 15, kg = lane >> 4;
  f32x4 acc = {0.f, 0.f, 0.f, 0.f};
  const unsigned short* pah = histh + (size_t)(m0 + row) * HID + kg * 8 + wave * 256;
  const unsigned short* pal = histl + (size_t)(m0 + row) * HID + kg * 8 + wave * 256;
  const unsigned short* pbh = wdh + (size_t)(n0 + row) * HID + kg * 8 + wave * 256;
#pragma unroll
  for (int kk = 0; kk < 8; ++kk) {
    int off = kk * 32;
    f16x8 a1 = ld8(pah + off), a2 = ld8(pal + off);
    f16x8 b1 = ld8(pbh + off);
    acc = __builtin_amdgcn_mfma_f32_16x16x32_f16(a1, b1, acc, 0, 0, 0);
    acc = __builtin_amdgcn_mfma_f32_16x16x32_f16(a2, b1, acc, 0, 0, 0);
  }
  __shared__ f32x4 red[4][64];
  if (wave) red[wave][lane] = acc;
  __syncthreads();
  if (wave == 0) {
    acc += red[1][lane];
    acc += red[2][lane];
    acc += red[3][lane];
    const int col = lane & 15, rg = lane >> 4;
#pragma unroll
    for (int r = 0; r < 4; ++r) {
      int m = m0 + rg * 4 + r;
      int n = n0 + col;
      if (n < OUTN) {
        int tt = m >> 7, b = m & 127;
        outp[(size_t)b * (GENF * OUTN) + (size_t)tt * OUTN + n] = acc[r] + bd[n];
      }
    }
  }
}

// ---- prep kernels ----
// LSTM weight -> PACKED: src [4096 gate-major rows][C] f32; perm row rp=(r&1023)*4+(r>>10);
// dst[((nt*NKW + ck0 + cc/32)*64 + (rp&63))*32 + cc%32] fp16, nt = rp>>6.
__global__ void cvt_w_pack_k(const float* __restrict__ src, unsigned short* __restrict__ dst,
                             int C, int Cpad, int ck0, int NKW)
{
  int idx = blockIdx.x * 256 + threadIdx.x;
  if (idx >= 4096 * Cpad) return;
  int r = idx / Cpad, cc = idx - r * Cpad;
  float v = (cc < C) ? src[(size_t)r * C + cc] : 0.f;
  int rp = (r & 1023) * 4 + (r >> 10);
  int nt = rp >> 6, nc = rp & 63;
  int ck = ck0 + (cc >> 5), kk = cc & 31;
  dst[(((size_t)nt * NKW + ck) * 64 + nc) * 32 + kk] = f2h(v);
}

// plain fp16 cvt with row/col pad (no perm)
__global__ void cvt_plain_k(const float* __restrict__ src, unsigned short* __restrict__ w16,
                            int R, int C, int Rp, int Cp)
{
  int idx = blockIdx.x * 256 + threadIdx.x;
  if (idx >= Rp * Cp) return;
  int r = idx / Cp, c2 = idx - r * Cp;
  float v = (r < R && c2 < C) ? src[(size_t)r * C + c2] : 0.f;
  w16[idx] = f2h(v);
}

// transposed dec weight: wdt[k][j] = w_dec[j][k], [1024][192] fp16 (pad j>=171 -> 0)
__global__ void cvt_wdt_k(const float* __restrict__ wdec, unsigned short* __restrict__ wdt)
{
  int idx = blockIdx.x * 256 + threadIdx.x;
  if (idx >= 1024 * 192) return;
  int k = idx / 192, j = idx - k * 192;
  float v = (j < OUTN) ? wdec[(size_t)j * HID + k] : 0.f;
  wdt[idx] = f2h(v);
}

// Weff = Wih1 @ Wd : [4096 perm rows][1024], written PACKED into W1g chunks 0..31.
__global__ __launch_bounds__(256) void weff_k(
    const unsigned short* __restrict__ wih, const unsigned short* __restrict__ wdt,
    unsigned short* __restrict__ W1g)
{
  const int wave = threadIdx.x >> 6, lane = threadIdx.x & 63;
  const int tile = blockIdx.x * 4 + wave;
  const int m0 = (tile >> 6) * 16;   // i
  const int n0 = (tile & 63) * 16;   // k2
  const int row = lane & 15, kg = lane >> 4;
  f32x4 acc = {0.f, 0.f, 0.f, 0.f};
  const unsigned short* pa = wih + (size_t)(m0 + row) * 192 + kg * 8;
  const unsigned short* pb = wdt + (size_t)(n0 + row) * 192 + kg * 8;
#pragma unroll
  for (int kk = 0; kk < 6; ++kk) {
    int off = kk * 32;
    f16x8 a = ld8(pa + off);
    f16x8 b = ld8(pb + off);
    acc = __builtin_amdgcn_mfma_f32_16x16x32_f16(a, b, acc, 0, 0, 0);
  }
  const int col = lane & 15, rg = lane >> 4;
#pragma unroll
  for (int r = 0; r < 4; ++r) {
    int i = m0 + rg * 4 + r;
    int k2 = n0 + col;
    int rp = (i & 1023) * 4 + (i >> 10);
    int nt = rp >> 6, nc = rp & 63;
    int ck = k2 >> 5, kk2 = k2 & 31;
    W1g[(((size_t)nt * 64 + ck) * 64 + nc) * 32 + kk2] = f2h(acc[r]);
  }
}

// beff[rp(i)] = b_ih1[i] + b_hh1[i] + sum_j Wih1[i][j] * b_dec[j]  (fp32)
__global__ void beff_k(const float* __restrict__ wih1, const float* __restrict__ bih,
                       const float* __restrict__ bhh, const float* __restrict__ bdec,
                       float* __restrict__ dst)
{
  int i = blockIdx.x * 256 + threadIdx.x;
  if (i >= 4096) return;
  float a = bih[i] + bhh[i];
  for (int j = 0; j < OUTN; ++j) a += wih1[(size_t)i * OUTN + j] * bdec[j];
  dst[(i & 1023) * 4 + (i >> 10)] = a;
}

__global__ void bias_perm_k(const float* __restrict__ a, const float* __restrict__ b,
                            float* __restrict__ dst)
{
  int i = blockIdx.x * 256 + threadIdx.x;
  if (i < 4096) dst[(i & 1023) * 4 + (i >> 10)] = a[i] + b[i];
}

__global__ void biaspad_k(const float* __restrict__ a, float* __restrict__ dst, int n, int np)
{
  int i = blockIdx.x * 256 + threadIdx.x;
  if (i < np) dst[i] = (i < n) ? a[i] : 0.f;
}

// initial_seq [B][T][IN] fp32 -> xcond hi/lo [T][B][INPAD] fp16
__global__ void xcond_k(const float* __restrict__ seq, unsigned short* __restrict__ xhi,
                        unsigned short* __restrict__ xlo)
{
  int idx = blockIdx.x * 256 + threadIdx.x;
  const int total = TCOND * BATCH * INPAD;
  if (idx >= total) return;
  int t = idx / (BATCH * INPAD);
  int rem = idx - t * (BATCH * INPAD);
  int b = rem / INPAD;
  int k = rem - b * INPAD;
  float v = (k < INP) ? seq[((size_t)b * TCOND + t) * INP + k] : 0.f;
  unsigned short h = f2h(v);
  xhi[idx] = h;
  xlo[idx] = f2h(v - h2f(h));
}

extern "C" void kernel_launch(void* const* d_in, const int* in_sizes, int n_in,
                              void* d_out, int out_size, void* d_ws, size_t ws_size,
                              hipStream_t stream)
{
  (void)in_sizes; (void)n_in; (void)out_size;
  const float* seq   = (const float*)d_in[0];
  const float* w_ih1 = (const float*)d_in[2];
  const float* w_hh1 = (const float*)d_in[3];
  const float* b_ih1 = (const float*)d_in[4];
  const float* b_hh1 = (const float*)d_in[5];
  const float* w_ih2 = (const float*)d_in[6];
  const float* w_hh2 = (const float*)d_in[7];
  const float* b_ih2 = (const float*)d_in[8];
  const float* b_hh2 = (const float*)d_in[9];
  const float* w_ih3 = (const float*)d_in[10];
  const float* w_hh3 = (const float*)d_in[11];
  const float* b_ih3 = (const float*)d_in[12];
  const float* b_hh3 = (const float*)d_in[13];
  const float* w_dec = (const float*)d_in[14];
  const float* b_dec = (const float*)d_in[15];
  float* out = (float*)d_out;

  char* ws = (char*)d_ws;
  size_t off = 0;
  auto alloc = [&](size_t bytes) -> char* {
    off = (off + 255) & ~(size_t)255;
    char* p = ws + off;
    off += bytes;
    return p;
  };
  auto us = [&](size_t n) { return (unsigned short*)alloc(n * 2); };
  auto fl = [&](size_t n) { return (float*)alloc(n * 4); };

  const int NK1C = 40;  // cond L1: 6 x-chunks + 32 h-chunks = 38 real, pad to 40 (nit=10 even)
  const int NK2 = 64;   // gen L1 / L2 / L3: 32 x + 32 h (nit=16)
  unsigned short* W1c = us((size_t)4096 * NK1C * 32);   // packed
  unsigned short* W1g = us((size_t)4096 * NK2 * 32);    // packed: ck0-31 Weff, 32-63 Whh1
  unsigned short* W2 = us((size_t)4096 * NK2 * 32);     // packed: Wih2 | Whh2
  unsigned short* W3 = us((size_t)4096 * NK2 * 32);     // packed: Wih3 | Whh3
  unsigned short* wd = us((size_t)OUTPAD * HID);
  unsigned short* wih1f = us((size_t)4096 * 192);
  unsigned short* wdt = us((size_t)1024 * 192);
  float *b1c = fl(4096), *beff = fl(4096), *b2 = fl(4096), *b3 = fl(4096), *bd = fl(OUTPAD);
  unsigned short *xch = us((size_t)TCOND * BATCH * INPAD), *xcl = us((size_t)TCOND * BATCH * INPAD);
  float* partials = fl((size_t)SPLITS * PSTR);
  unsigned short* histh = us((size_t)GENF * BATCH * HID);
  unsigned short* histl = us((size_t)GENF * BATCH * HID);

  size_t state_beg = (off + 255) & ~(size_t)255;
  float *c0 = fl((size_t)BATCH * HID), *c1 = fl((size_t)BATCH * HID), *c2 = fl((size_t)BATCH * HID);
  unsigned short* Hh[3][2];
  unsigned short* Hl[3][2];
  for (int L = 0; L < 3; ++L)
    for (int p = 0; p < 2; ++p) {
      Hh[L][p] = us((size_t)BATCH * HID);
      Hl[L][p] = us((size_t)BATCH * HID);
    }
  unsigned* counters = (unsigned*)alloc(3 * TILES * 4);  // monotonic, zeroed each call
  size_t state_end = off;

  if (off > ws_size) return;  // scratch too small; fail visibly

  hipMemsetAsync(ws + state_beg, 0, state_end - state_beg, stream);
  // zero W1c pad chunks (38..39)
  hipMemsetAsync(W1c, 0, (size_t)4096 * NK1C * 32 * 2, stream);

  // ---- weight / input prep ----
  cvt_w_pack_k<<<(4096 * INPAD + 255) / 256, 256, 0, stream>>>(w_ih1, W1c, INP, INPAD, 0, NK1C);
  cvt_w_pack_k<<<(4096 * 1024 + 255) / 256, 256, 0, stream>>>(w_hh1, W1c, HID, HID, 6, NK1C);
  cvt_w_pack_k<<<(4096 * 1024 + 255) / 256, 256, 0, stream>>>(w_hh1, W1g, HID, HID, 32, NK2);
  cvt_w_pack_k<<<(4096 * 1024 + 255) / 256, 256, 0, stream>>>(w_ih2, W2, HID, HID, 0, NK2);
  cvt_w_pack_k<<<(4096 * 1024 + 255) / 256, 256, 0, stream>>>(w_hh2, W2, HID, HID, 32, NK2);
  cvt_w_pack_k<<<(4096 * 1024 + 255) / 256, 256, 0, stream>>>(w_ih3, W3, HID, HID, 0, NK2);
  cvt_w_pack_k<<<(4096 * 1024 + 255) / 256, 256, 0, stream>>>(w_hh3, W3, HID, HID, 32, NK2);
  cvt_plain_k<<<(OUTPAD * HID + 255) / 256, 256, 0, stream>>>(w_dec, wd, OUTN, HID, OUTPAD, HID);
  cvt_plain_k<<<(4096 * 192 + 255) / 256, 256, 0, stream>>>(w_ih1, wih1f, 4096, INP, 4096, 192);
  cvt_wdt_k<<<(1024 * 192 + 255) / 256, 256, 0, stream>>>(w_dec, wdt);
  weff_k<<<4096, 256, 0, stream>>>(wih1f, wdt, W1g);
  beff_k<<<16, 256, 0, stream>>>(w_ih1, b_ih1, b_hh1, b_dec, beff);
  bias_perm_k<<<16, 256, 0, stream>>>(b_ih1, b_hh1, b1c);
  bias_perm_k<<<16, 256, 0, stream>>>(b_ih2, b_hh2, b2);
  bias_perm_k<<<16, 256, 0, stream>>>(b_ih3, b_hh3, b3);
  biaspad_k<<<1, 256, 0, stream>>>(b_dec, bd, OUTN, OUTPAD);
  xcond_k<<<(TCOND * BATCH * INPAD + 255) / 256, 256, 0, stream>>>(seq, xch, xcl);

  // ---- recurrent loop: 3 dispatches per step (decoder folded into gen-L1) ----
  for (int s = 0; s < TCOND + GENF; ++s) {
    const int pp = s & 1, np = pp ^ 1;
    const unsigned tg = (unsigned)SPLITS * (unsigned)(s + 1);
    unsigned short *hsh = (unsigned short*)0, *hsl = (unsigned short*)0;
    if (s >= TCOND) {
      hsh = histh + (size_t)(s - TCOND) * BATCH * HID;
      hsl = histl + (size_t)(s - TCOND) * BATCH * HID;
    }
    if (s < TCOND) {
      lstm_gemm_k<<<TILES * SPLITS, 256, 0, stream>>>(
          xch + (size_t)s * BATCH * INPAD, xcl + (size_t)s * BATCH * INPAD, INPAD, 6,
          Hh[0][pp], Hl[0][pp], W1c, NK1C, 38, b1c, c0,
          Hh[0][np], Hl[0][np], (unsigned short*)0, (unsigned short*)0,
          partials, counters, tg);
    } else {
      lstm_gemm_k<<<TILES * SPLITS, 256, 0, stream>>>(
          Hh[2][pp], Hl[2][pp], HID, 32,
          Hh[0][pp], Hl[0][pp], W1g, NK2, NK2, beff, c0,
          Hh[0][np], Hl[0][np], (unsigned short*)0, (unsigned short*)0,
          partials, counters, tg);
    }
    lstm_gemm_k<<<TILES * SPLITS, 256, 0, stream>>>(
        Hh[0][np], Hl[0][np], HID, 32,
        Hh[1][pp], Hl[1][pp], W2, NK2, NK2, b2, c1,
        Hh[1][np], Hl[1][np], (unsigned short*)0, (unsigned short*)0,
        partials, counters + TILES, tg);
    lstm_gemm_k<<<TILES * SPLITS, 256, 0, stream>>>(
        Hh[1][np], Hl[1][np], HID, 32,
        Hh[2][pp], Hl[2][pp], W3, NK2, NK2, b3, c2,
        Hh[2][np], Hl[2][np], hsh, hsl,
        partials, counters + 2 * TILES, tg);
  }

  // ---- batched decoder: all 100 outputs in one GEMM ----
  decb_k<<<(GENF * BATCH / 16) * 11, 256, 0, stream>>>(histh, histl, wd, bd, out);
}